// Round 2
// baseline (206.895 us; speedup 1.0000x reference)
//
#include <hip/hip_runtime.h>

typedef __attribute__((ext_vector_type(8))) short bf16x8;
typedef __attribute__((ext_vector_type(4))) float f32x4;
typedef __attribute__((ext_vector_type(16))) float f32x16;
typedef __attribute__((ext_vector_type(4))) unsigned short u16x4;

#define DIM 1024
#define SEQ 2048
#define NHEAD 16
#define HDIM 64
// 0.125 * log2(e): folds the 1/sqrt(64) scale into exp2 space
#define C2 0.18033688011112042f

__device__ __forceinline__ unsigned short f2bf(float f) {
  union { float f; unsigned u; } v; v.f = f;
  unsigned r = v.u + 0x7fffu + ((v.u >> 16) & 1u);
  return (unsigned short)(r >> 16);
}

__device__ __forceinline__ void gload_lds16(const void* g, void* l) {
  __builtin_amdgcn_global_load_lds(
      (const __attribute__((address_space(1))) void*)g,
      (__attribute__((address_space(3))) void*)l, 16, 0, 0);
}

__device__ __forceinline__ f32x16 mfma32(bf16x8 a, bf16x8 b, f32x16 c) {
  return __builtin_amdgcn_mfma_f32_32x32x16_bf16(a, b, c, 0, 0, 0);
}

__device__ __forceinline__ unsigned cvtpk(float lo, float hi) {
  unsigned r;
  asm("v_cvt_pk_bf16_f32 %0, %1, %2" : "=v"(r) : "v"(lo), "v"(hi));
  return r;
}

// ---------------- fused fp32 -> bf16 conversion (x + 4 weights) ----------------
__global__ void f2bf_all(const float* __restrict__ x, const float* __restrict__ wq,
                         const float* __restrict__ wk, const float* __restrict__ wv,
                         const float* __restrict__ wo, unsigned short* __restrict__ xb,
                         unsigned short* __restrict__ wb) {
  int blk = blockIdx.x;
  const float* src;
  unsigned short* dst;
  int rb;
  if (blk < 4096) { src = x; dst = xb; rb = blk; }
  else {
    int w = (blk - 4096) >> 10;
    src = w == 0 ? wq : w == 1 ? wk : w == 2 ? wv : wo;
    dst = wb + (size_t)w * 1048576;
    rb = (blk - 4096) & 1023;
  }
  int i = rb * 256 + threadIdx.x;  // float4 index
  float4 v = ((const float4*)src)[i];
  u16x4 o;
  o[0] = f2bf(v.x); o[1] = f2bf(v.y); o[2] = f2bf(v.z); o[3] = f2bf(v.w);
  ((u16x4*)dst)[i] = o;
}

// ---------------- NT GEMM: C[m,n] = sum_k A[m,k] * B[n,k] ----------------
template <bool F32OUT>
__global__ __launch_bounds__(256) void gemm_nt(
    const unsigned short* __restrict__ A,
    const unsigned short* __restrict__ Ball,
    void* __restrict__ Call,
    int K, int N, long long wstride, long long cstride) {
  __shared__ unsigned short As[128 * 64];
  __shared__ unsigned short Bs[128 * 64];
  const int tid = threadIdx.x;
  const int wv = tid >> 6, lane = tid & 63;
  const int g = lane >> 4, l16 = lane & 15;
  const int m0 = blockIdx.y * 128, n0 = blockIdx.x * 128;
  const unsigned short* B = Ball + (long long)blockIdx.z * wstride;
  const int wm = (wv >> 1) * 64, wn = (wv & 1) * 64;
  f32x4 acc[4][4] = {};

  for (int kt = 0; kt < K; kt += 64) {
    __syncthreads();
#pragma unroll
    for (int qq = 0; qq < 4; ++qq) {
      int rbase = wv * 32 + qq * 8;
      int r = rbase + (lane >> 3);
      int cs = ((lane & 7) ^ (r & 7)) * 8;  // pre-swizzled source chunk
      gload_lds16(A + (long long)(m0 + r) * K + kt + cs, &As[rbase * 64]);
      gload_lds16(B + (long long)(n0 + r) * K + kt + cs, &Bs[rbase * 64]);
    }
    __syncthreads();
#pragma unroll
    for (int ks = 0; ks < 2; ++ks) {
      bf16x8 af[4], bfr[4];
      const int cb = ks * 64 + g * 16;
#pragma unroll
      for (int mf = 0; mf < 4; ++mf) {
        int row = wm + mf * 16 + l16;
        af[mf] = *(const bf16x8*)((const char*)As + row * 128 + (cb ^ ((row & 7) << 4)));
      }
#pragma unroll
      for (int nf = 0; nf < 4; ++nf) {
        int row = wn + nf * 16 + l16;
        bfr[nf] = *(const bf16x8*)((const char*)Bs + row * 128 + (cb ^ ((row & 7) << 4)));
      }
#pragma unroll
      for (int mf = 0; mf < 4; ++mf)
#pragma unroll
        for (int nf = 0; nf < 4; ++nf)
          acc[mf][nf] = __builtin_amdgcn_mfma_f32_16x16x32_bf16(
              af[mf], bfr[nf], acc[mf][nf], 0, 0, 0);
    }
  }

#pragma unroll
  for (int mf = 0; mf < 4; ++mf)
#pragma unroll
    for (int nf = 0; nf < 4; ++nf)
#pragma unroll
      for (int r = 0; r < 4; ++r) {
        long long m = m0 + wm + mf * 16 + g * 4 + r;
        long long n = n0 + wn + nf * 16 + l16;
        float v = acc[mf][nf][r];
        if (F32OUT)
          ((float*)Call)[(long long)blockIdx.z * cstride + m * N + n] = v;
        else
          ((unsigned short*)Call)[(long long)blockIdx.z * cstride + m * N + n] = f2bf(v);
      }
}

// ---------------- flash attention: 1 wave per 32-row q-tile, no LDS, no barriers ----
// grid (64, 16, 2), block 64. qt = 63 - bx (longest-first). KBLK=64 via 2x 32-key blocks.
// Swapped QK^T with 32x32x16 MFMA: S^T[key][q], col=lane&31=q.
// P redistributed in-register: v_cvt_pk_bf16_f32 + v_permlane32_swap_b32.
// PV: O^T[d][q] = sum VT[d][key] * P^T[key][q]; VT pre-transposed in global.
__global__ __launch_bounds__(64) void attn_kernel(
    const unsigned short* __restrict__ Qg,
    const unsigned short* __restrict__ Kg,
    const unsigned short* __restrict__ VTg,
    unsigned short* __restrict__ Og) {
  const int lane = threadIdx.x;
  const int l32 = lane & 31, hi = lane >> 5;
  const int qt = 63 - blockIdx.x;
  const int h = blockIdx.y, b = blockIdx.z;
  const int q = qt * 32 + l32;

  // Q fragments (B-operand): B[col=q][k = hi*8+j], per 16-d slice
  const unsigned short* Qrow = Qg + ((long long)(b * SEQ + q)) * DIM + h * HDIM;
  bf16x8 qf[4];
#pragma unroll
  for (int ds = 0; ds < 4; ++ds)
    qf[ds] = *(const bf16x8*)(Qrow + ds * 16 + hi * 8);

  f32x16 acc0 = {}, acc1 = {};
  float m_run = -1e30f, l_run = 0.f;

  const unsigned short* Kbase = Kg + ((long long)b * SEQ) * DIM + h * HDIM + hi * 8;
  const unsigned short* Vbase = VTg + ((long long)h * HDIM) * 4096 + b * SEQ + hi * 8;

  const int nt = (qt >> 1) + 1;
  for (int t = 0; t < nt; ++t) {
    const int kv0 = t * 64;
    // --- K fragments: A[row=key(lane&31)][k=hi*8+j] ---
    bf16x8 kf[8];
#pragma unroll
    for (int mf = 0; mf < 2; ++mf)
#pragma unroll
      for (int ds = 0; ds < 4; ++ds)
        kf[mf * 4 + ds] =
            *(const bf16x8*)(Kbase + (long long)(kv0 + mf * 32 + l32) * DIM + ds * 16);
    // --- QK^T ---
    f32x16 s0 = {}, s1 = {};
#pragma unroll
    for (int ds = 0; ds < 4; ++ds) {
      s0 = mfma32(kf[ds], qf[ds], s0);
      s1 = mfma32(kf[4 + ds], qf[ds], s1);
    }
    // --- issue VT loads now; latency hides under softmax ---
    bf16x8 vf[8];
#pragma unroll
    for (int dblk = 0; dblk < 2; ++dblk)
#pragma unroll
      for (int kks = 0; kks < 4; ++kks)
        vf[dblk * 4 + kks] =
            *(const bf16x8*)(Vbase + (long long)(dblk * 32 + l32) * 4096 + kv0 + kks * 16);

    // --- causal mask (only last k-tile can touch the diagonal) ---
    if (t == nt - 1) {
#pragma unroll
      for (int r = 0; r < 16; ++r) {
        int kw = (r & 3) + 8 * (r >> 2) + 4 * hi;  // key within 32-block
        if (kv0 + kw > q) s0[r] = -1e30f;
        if (kv0 + 32 + kw > q) s1[r] = -1e30f;
      }
    }

    // --- online softmax (raw-score space; scale folded into exp2) ---
    float pm = -1e30f;
#pragma unroll
    for (int r = 0; r < 16; ++r) pm = fmaxf(pm, fmaxf(s0[r], s1[r]));
    pm = fmaxf(pm, __shfl_xor(pm, 32));
    if (!__all(pm - m_run <= 44.3614f)) {  // defer-max: skip rescale if growth < 8/C2
      float m_new = fmaxf(m_run, pm);
      float rs = exp2f((m_run - m_new) * C2);
      l_run *= rs;
#pragma unroll
      for (int r = 0; r < 16; ++r) { acc0[r] *= rs; acc1[r] *= rs; }
      m_run = m_new;
    }
    float l_add = 0.f;
    const float mc = m_run * C2;
#pragma unroll
    for (int r = 0; r < 16; ++r) {
      float p0 = exp2f(s0[r] * C2 - mc);
      float p1 = exp2f(s1[r] * C2 - mc);
      s0[r] = p0; s1[r] = p1;
      l_add += p0 + p1;
    }
    l_add += __shfl_xor(l_add, 32);
    l_run += l_add;

    // --- P -> bf16 B-fragments (in-register) + PV ---
#pragma unroll
    for (int kks = 0; kks < 4; ++kks) {
      const int base = (kks & 1) * 8;
      unsigned a0, a1, a2, a3;
      if (kks < 2) {
        a0 = cvtpk(s0[base + 0], s0[base + 1]);
        a1 = cvtpk(s0[base + 2], s0[base + 3]);
        a2 = cvtpk(s0[base + 4], s0[base + 5]);
        a3 = cvtpk(s0[base + 6], s0[base + 7]);
      } else {
        a0 = cvtpk(s1[base + 0], s1[base + 1]);
        a1 = cvtpk(s1[base + 2], s1[base + 3]);
        a2 = cvtpk(s1[base + 4], s1[base + 5]);
        a3 = cvtpk(s1[base + 6], s1[base + 7]);
      }
      asm("v_permlane32_swap_b32 %0, %1" : "+v"(a0), "+v"(a2));
      asm("v_permlane32_swap_b32 %0, %1" : "+v"(a1), "+v"(a3));
      union { unsigned u[4]; bf16x8 v; } pf;
      pf.u[0] = a0; pf.u[1] = a1; pf.u[2] = a2; pf.u[3] = a3;
      acc0 = mfma32(vf[kks], pf.v, acc0);
      acc1 = mfma32(vf[4 + kks], pf.v, acc1);
    }
  }

  // --- epilogue: O[b, q, h*64 + d] = acc^T / l ---
  const float inv_l = 1.0f / l_run;
  unsigned short* Orow = Og + ((long long)(b * SEQ + q)) * DIM + h * HDIM;
#pragma unroll
  for (int dblk = 0; dblk < 2; ++dblk) {
#pragma unroll
    for (int g4 = 0; g4 < 4; ++g4) {
      u16x4 o;
#pragma unroll
      for (int j = 0; j < 4; ++j) {
        float v = (dblk ? acc1[g4 * 4 + j] : acc0[g4 * 4 + j]) * inv_l;
        o[j] = f2bf(v);
      }
      *(u16x4*)(Orow + dblk * 32 + 8 * g4 + 4 * hi) = o;
    }
  }
}

// ---------------- launcher ----------------
extern "C" void kernel_launch(void* const* d_in, const int* in_sizes, int n_in,
                              void* d_out, int out_size, void* d_ws, size_t ws_size,
                              hipStream_t stream) {
  const float* x   = (const float*)d_in[0];
  const float* wq  = (const float*)d_in[2];
  const float* wk  = (const float*)d_in[3];
  const float* wv_ = (const float*)d_in[4];
  const float* wo  = (const float*)d_in[5];

  unsigned short* xb  = (unsigned short*)d_ws;            // [4096][1024]
  unsigned short* wb  = xb + (size_t)4096 * 1024;         // [4][1024][1024] q,k,v,o
  unsigned short* qkv = wb + (size_t)4 * 1024 * 1024;     // Q,K [4096][1024]; VT [1024][4096]
  unsigned short* ao  = qkv + (size_t)3 * 4096 * 1024;    // [4096][1024]

  f2bf_all<<<8192, 256, 0, stream>>>(x, wq, wk, wv_, wo, xb, wb);

  // Q,K projections (z selects weight/output)
  gemm_nt<false><<<dim3(8, 32, 2), 256, 0, stream>>>(
      xb, wb, qkv, 1024, 1024, 1048576LL, 4194304LL);

  // V^T projection: C[n_v][token] = sum_k wv[n_v,k] x[token,k]  (A/B roles swapped)
  gemm_nt<false><<<dim3(32, 8, 1), 256, 0, stream>>>(
      wb + 2 * 1048576, xb, qkv + 2 * 4194304, 1024, 4096, 0LL, 0LL);

  attn_kernel<<<dim3(64, 16, 2), 64, 0, stream>>>(
      qkv, qkv + 4194304, qkv + 2 * 4194304, ao);

  // output projection -> fp32 d_out
  gemm_nt<true><<<dim3(8, 32, 1), 256, 0, stream>>>(
      ao, wb + 3145728, d_out, 1024, 1024, 0LL, 0LL);
}

// Round 3
// 188.209 us; speedup vs baseline: 1.0993x; 1.0993x over previous
//
#include <hip/hip_runtime.h>

typedef __attribute__((ext_vector_type(8))) short bf16x8;
typedef __attribute__((ext_vector_type(4))) float f32x4;
typedef __attribute__((ext_vector_type(16))) float f32x16;
typedef __attribute__((ext_vector_type(4))) unsigned short u16x4;

#define DIM 1024
#define SEQ 2048
#define NHEAD 16
#define HDIM 64
// 0.125 * log2(e): folds the 1/sqrt(64) scale into exp2 space
#define C2 0.18033688011112042f

__device__ __forceinline__ unsigned short f2bf(float f) {
  union { float f; unsigned u; } v; v.f = f;
  unsigned r = v.u + 0x7fffu + ((v.u >> 16) & 1u);
  return (unsigned short)(r >> 16);
}

__device__ __forceinline__ void gload_lds16(const void* g, void* l) {
  __builtin_amdgcn_global_load_lds(
      (const __attribute__((address_space(1))) void*)g,
      (__attribute__((address_space(3))) void*)l, 16, 0, 0);
}

__device__ __forceinline__ f32x16 mfma32(bf16x8 a, bf16x8 b, f32x16 c) {
  return __builtin_amdgcn_mfma_f32_32x32x16_bf16(a, b, c, 0, 0, 0);
}

__device__ __forceinline__ unsigned cvtpk(float lo, float hi) {
  unsigned r;
  asm("v_cvt_pk_bf16_f32 %0, %1, %2" : "=v"(r) : "v"(lo), "v"(hi));
  return r;
}

// ---------------- fused fp32 -> bf16 conversion (x + 4 weights) ----------------
__global__ void f2bf_all(const float* __restrict__ x, const float* __restrict__ wq,
                         const float* __restrict__ wk, const float* __restrict__ wv,
                         const float* __restrict__ wo, unsigned short* __restrict__ xb,
                         unsigned short* __restrict__ wb) {
  int blk = blockIdx.x;
  const float* src;
  unsigned short* dst;
  int rb;
  if (blk < 4096) { src = x; dst = xb; rb = blk; }
  else {
    int w = (blk - 4096) >> 10;
    src = w == 0 ? wq : w == 1 ? wk : w == 2 ? wv : wo;
    dst = wb + (size_t)w * 1048576;
    rb = (blk - 4096) & 1023;
  }
  int i = rb * 256 + threadIdx.x;  // float4 index
  float4 v = ((const float4*)src)[i];
  u16x4 o;
  o[0] = f2bf(v.x); o[1] = f2bf(v.y); o[2] = f2bf(v.z); o[3] = f2bf(v.w);
  ((u16x4*)dst)[i] = o;
}

// ---------------- NT GEMM: C[m,n] = sum_k A[m,k] * B[n,k] ----------------
template <bool F32OUT>
__global__ __launch_bounds__(256) void gemm_nt(
    const unsigned short* __restrict__ A,
    const unsigned short* __restrict__ Ball,
    void* __restrict__ Call,
    int K, int N, long long wstride, long long cstride) {
  __shared__ unsigned short As[128 * 64];
  __shared__ unsigned short Bs[128 * 64];
  const int tid = threadIdx.x;
  const int wv = tid >> 6, lane = tid & 63;
  const int g = lane >> 4, l16 = lane & 15;
  const int m0 = blockIdx.y * 128, n0 = blockIdx.x * 128;
  const unsigned short* B = Ball + (long long)blockIdx.z * wstride;
  const int wm = (wv >> 1) * 64, wn = (wv & 1) * 64;
  f32x4 acc[4][4] = {};

  for (int kt = 0; kt < K; kt += 64) {
    __syncthreads();
#pragma unroll
    for (int qq = 0; qq < 4; ++qq) {
      int rbase = wv * 32 + qq * 8;
      int r = rbase + (lane >> 3);
      int cs = ((lane & 7) ^ (r & 7)) * 8;  // pre-swizzled source chunk
      gload_lds16(A + (long long)(m0 + r) * K + kt + cs, &As[rbase * 64]);
      gload_lds16(B + (long long)(n0 + r) * K + kt + cs, &Bs[rbase * 64]);
    }
    __syncthreads();
#pragma unroll
    for (int ks = 0; ks < 2; ++ks) {
      bf16x8 af[4], bfr[4];
      const int cb = ks * 64 + g * 16;
#pragma unroll
      for (int mf = 0; mf < 4; ++mf) {
        int row = wm + mf * 16 + l16;
        af[mf] = *(const bf16x8*)((const char*)As + row * 128 + (cb ^ ((row & 7) << 4)));
      }
#pragma unroll
      for (int nf = 0; nf < 4; ++nf) {
        int row = wn + nf * 16 + l16;
        bfr[nf] = *(const bf16x8*)((const char*)Bs + row * 128 + (cb ^ ((row & 7) << 4)));
      }
#pragma unroll
      for (int mf = 0; mf < 4; ++mf)
#pragma unroll
        for (int nf = 0; nf < 4; ++nf)
          acc[mf][nf] = __builtin_amdgcn_mfma_f32_16x16x32_bf16(
              af[mf], bfr[nf], acc[mf][nf], 0, 0, 0);
    }
  }

#pragma unroll
  for (int mf = 0; mf < 4; ++mf)
#pragma unroll
    for (int nf = 0; nf < 4; ++nf)
#pragma unroll
      for (int r = 0; r < 4; ++r) {
        long long m = m0 + wm + mf * 16 + g * 4 + r;
        long long n = n0 + wn + nf * 16 + l16;
        float v = acc[mf][nf][r];
        if (F32OUT)
          ((float*)Call)[(long long)blockIdx.z * cstride + m * N + n] = v;
        else
          ((unsigned short*)Call)[(long long)blockIdx.z * cstride + m * N + n] = f2bf(v);
      }
}

// ---------------- flash attention: 4 waves split-K over one 32-row q-tile --------
// grid (64, 16, 2), block 256. qt = 63 - bx (longest-first). Wave w does k-tiles
// t = w, w+4, ... with private online-softmax state; LDS merge at the end.
// Swapped QK^T with 32x32x16 MFMA: S^T[key][q], col=lane&31=q.
// P redistributed in-register: v_cvt_pk_bf16_f32 + v_permlane32_swap_b32.
// PV: O^T[d][q] = sum VT[d][key] * P^T[key][q]; VT pre-transposed in global.
__global__ __launch_bounds__(256) void attn_kernel(
    const unsigned short* __restrict__ Qg,
    const unsigned short* __restrict__ Kg,
    const unsigned short* __restrict__ VTg,
    unsigned short* __restrict__ Og) {
  __shared__ float accL[3][32][64];   // [wave-1][reg r][lane] — lane-minor, conflict-free
  __shared__ float mlL[3][2][32];     // [wave-1][m|l][q=l32]

  const int tid = threadIdx.x;
  const int wv = tid >> 6, lane = tid & 63;
  const int l32 = lane & 31, hi = lane >> 5;
  const int qt = 63 - blockIdx.x;
  const int h = blockIdx.y, b = blockIdx.z;
  const int q = qt * 32 + l32;

  // Q fragments (B-operand): B[col=q][k = hi*8+j], per 16-d slice
  const unsigned short* Qrow = Qg + ((long long)(b * SEQ + q)) * DIM + h * HDIM;
  bf16x8 qf[4];
#pragma unroll
  for (int ds = 0; ds < 4; ++ds)
    qf[ds] = *(const bf16x8*)(Qrow + ds * 16 + hi * 8);

  f32x16 acc0 = {}, acc1 = {};
  float m_run = -1e30f, l_run = 0.f;

  const unsigned short* Kbase = Kg + ((long long)b * SEQ) * DIM + h * HDIM + hi * 8;
  const unsigned short* Vbase = VTg + ((long long)h * HDIM) * 4096 + b * SEQ + hi * 8;

  const int nt = (qt >> 1) + 1;
  for (int t = wv; t < nt; t += 4) {
    const int kv0 = t * 64;
    // --- K fragments: A[row=key(lane&31)][k=hi*8+j] ---
    bf16x8 kf[8];
#pragma unroll
    for (int mf = 0; mf < 2; ++mf)
#pragma unroll
      for (int ds = 0; ds < 4; ++ds)
        kf[mf * 4 + ds] =
            *(const bf16x8*)(Kbase + (long long)(kv0 + mf * 32 + l32) * DIM + ds * 16);
    // --- QK^T ---
    f32x16 s0 = {}, s1 = {};
#pragma unroll
    for (int ds = 0; ds < 4; ++ds) {
      s0 = mfma32(kf[ds], qf[ds], s0);
      s1 = mfma32(kf[4 + ds], qf[ds], s1);
    }
    // --- issue VT loads now; latency hides under softmax ---
    bf16x8 vf[8];
#pragma unroll
    for (int dblk = 0; dblk < 2; ++dblk)
#pragma unroll
      for (int kks = 0; kks < 4; ++kks)
        vf[dblk * 4 + kks] =
            *(const bf16x8*)(Vbase + (long long)(dblk * 32 + l32) * 4096 + kv0 + kks * 16);

    // --- causal mask (only tiles touching the diagonal) ---
    if (kv0 + 64 > q) {
#pragma unroll
      for (int r = 0; r < 16; ++r) {
        int kw = (r & 3) + 8 * (r >> 2) + 4 * hi;  // key within 32-block
        if (kv0 + kw > q) s0[r] = -1e30f;
        if (kv0 + 32 + kw > q) s1[r] = -1e30f;
      }
    }

    // --- online softmax (raw-score space; scale folded into exp2) ---
    float pm = -1e30f;
#pragma unroll
    for (int r = 0; r < 16; ++r) pm = fmaxf(pm, fmaxf(s0[r], s1[r]));
    pm = fmaxf(pm, __shfl_xor(pm, 32));
    if (!__all(pm - m_run <= 44.3614f)) {  // defer-max: skip rescale if growth < 8/C2
      float m_new = fmaxf(m_run, pm);
      float rs = exp2f((m_run - m_new) * C2);
      l_run *= rs;
#pragma unroll
      for (int r = 0; r < 16; ++r) { acc0[r] *= rs; acc1[r] *= rs; }
      m_run = m_new;
    }
    float l_add = 0.f;
    const float mc = m_run * C2;
#pragma unroll
    for (int r = 0; r < 16; ++r) {
      float p0 = exp2f(s0[r] * C2 - mc);
      float p1 = exp2f(s1[r] * C2 - mc);
      s0[r] = p0; s1[r] = p1;
      l_add += p0 + p1;
    }
    l_add += __shfl_xor(l_add, 32);
    l_run += l_add;

    // --- P -> bf16 B-fragments (in-register) + PV ---
#pragma unroll
    for (int kks = 0; kks < 4; ++kks) {
      const int base = (kks & 1) * 8;
      unsigned a0, a1, a2, a3;
      if (kks < 2) {
        a0 = cvtpk(s0[base + 0], s0[base + 1]);
        a1 = cvtpk(s0[base + 2], s0[base + 3]);
        a2 = cvtpk(s0[base + 4], s0[base + 5]);
        a3 = cvtpk(s0[base + 6], s0[base + 7]);
      } else {
        a0 = cvtpk(s1[base + 0], s1[base + 1]);
        a1 = cvtpk(s1[base + 2], s1[base + 3]);
        a2 = cvtpk(s1[base + 4], s1[base + 5]);
        a3 = cvtpk(s1[base + 6], s1[base + 7]);
      }
      asm("v_permlane32_swap_b32 %0, %1" : "+v"(a0), "+v"(a2));
      asm("v_permlane32_swap_b32 %0, %1" : "+v"(a1), "+v"(a3));
      union { unsigned u[4]; bf16x8 v; } pf;
      pf.u[0] = a0; pf.u[1] = a1; pf.u[2] = a2; pf.u[3] = a3;
      acc0 = mfma32(vf[kks], pf.v, acc0);
      acc1 = mfma32(vf[4 + kks], pf.v, acc1);
    }
  }

  // --- cross-wave merge: waves 1-3 dump partial state; wave 0 combines ---
  if (wv > 0) {
#pragma unroll
    for (int r = 0; r < 16; ++r) {
      accL[wv - 1][r][lane] = acc0[r];
      accL[wv - 1][16 + r][lane] = acc1[r];
    }
    if (hi == 0) {
      mlL[wv - 1][0][l32] = m_run;
      mlL[wv - 1][1][l32] = l_run;
    }
  }
  __syncthreads();
  if (wv > 0) return;

#pragma unroll
  for (int w = 0; w < 3; ++w) {
    float mw = mlL[w][0][l32], lw = mlL[w][1][l32];
    float m_new = fmaxf(m_run, mw);
    float rs = exp2f((m_run - m_new) * C2);
    float ro = exp2f((mw - m_new) * C2);
#pragma unroll
    for (int r = 0; r < 16; ++r) {
      acc0[r] = acc0[r] * rs + accL[w][r][lane] * ro;
      acc1[r] = acc1[r] * rs + accL[w][16 + r][lane] * ro;
    }
    l_run = l_run * rs + lw * ro;
    m_run = m_new;
  }

  // --- epilogue: O[b, q, h*64 + d] = acc^T / l ---
  const float inv_l = 1.0f / l_run;
  unsigned short* Orow = Og + ((long long)(b * SEQ + q)) * DIM + h * HDIM;
#pragma unroll
  for (int dblk = 0; dblk < 2; ++dblk) {
#pragma unroll
    for (int g4 = 0; g4 < 4; ++g4) {
      u16x4 o;
#pragma unroll
      for (int j = 0; j < 4; ++j) {
        float v = (dblk ? acc1[g4 * 4 + j] : acc0[g4 * 4 + j]) * inv_l;
        o[j] = f2bf(v);
      }
      *(u16x4*)(Orow + dblk * 32 + 8 * g4 + 4 * hi) = o;
    }
  }
}

// ---------------- launcher ----------------
extern "C" void kernel_launch(void* const* d_in, const int* in_sizes, int n_in,
                              void* d_out, int out_size, void* d_ws, size_t ws_size,
                              hipStream_t stream) {
  const float* x   = (const float*)d_in[0];
  const float* wq  = (const float*)d_in[2];
  const float* wk  = (const float*)d_in[3];
  const float* wv_ = (const float*)d_in[4];
  const float* wo  = (const float*)d_in[5];

  unsigned short* xb  = (unsigned short*)d_ws;            // [4096][1024]
  unsigned short* wb  = xb + (size_t)4096 * 1024;         // [4][1024][1024] q,k,v,o
  unsigned short* qkv = wb + (size_t)4 * 1024 * 1024;     // Q,K [4096][1024]; VT [1024][4096]
  unsigned short* ao  = qkv + (size_t)3 * 4096 * 1024;    // [4096][1024]

  f2bf_all<<<8192, 256, 0, stream>>>(x, wq, wk, wv_, wo, xb, wb);

  // Q,K projections (z selects weight/output)
  gemm_nt<false><<<dim3(8, 32, 2), 256, 0, stream>>>(
      xb, wb, qkv, 1024, 1024, 1048576LL, 4194304LL);

  // V^T projection: C[n_v][token] = sum_k wv[n_v,k] x[token,k]  (A/B roles swapped)
  gemm_nt<false><<<dim3(32, 8, 1), 256, 0, stream>>>(
      wb + 2 * 1048576, xb, qkv + 2 * 4194304, 1024, 4096, 0LL, 0LL);

  attn_kernel<<<dim3(64, 16, 2), 256, 0, stream>>>(
      qkv, qkv + 4194304, qkv + 2 * 4194304, ao);

  // output projection -> fp32 d_out
  gemm_nt<true><<<dim3(8, 32, 1), 256, 0, stream>>>(
      ao, wb + 3145728, d_out, 1024, 1024, 0LL, 0LL);
}

// Round 4
// 158.464 us; speedup vs baseline: 1.3056x; 1.1877x over previous
//
#include <hip/hip_runtime.h>

typedef __attribute__((ext_vector_type(8))) short bf16x8;
typedef __attribute__((ext_vector_type(4))) float f32x4;
typedef __attribute__((ext_vector_type(16))) float f32x16;
typedef __attribute__((ext_vector_type(4))) unsigned short u16x4;

#define DIM 1024
#define SEQ 2048
#define NHEAD 16
#define HDIM 64
// 0.125 * log2(e): folds the 1/sqrt(64) scale into exp2 space
#define C2 0.18033688011112042f

__device__ __forceinline__ unsigned short f2bf(float f) {
  union { float f; unsigned u; } v; v.f = f;
  unsigned r = v.u + 0x7fffu + ((v.u >> 16) & 1u);
  return (unsigned short)(r >> 16);
}

__device__ __forceinline__ void gload_lds16(const void* g, void* l) {
  __builtin_amdgcn_global_load_lds(
      (const __attribute__((address_space(1))) void*)g,
      (__attribute__((address_space(3))) void*)l, 16, 0, 0);
}

__device__ __forceinline__ f32x16 mfma32(bf16x8 a, bf16x8 b, f32x16 c) {
  return __builtin_amdgcn_mfma_f32_32x32x16_bf16(a, b, c, 0, 0, 0);
}

__device__ __forceinline__ unsigned cvtpk(float lo, float hi) {
  unsigned r;
  asm("v_cvt_pk_bf16_f32 %0, %1, %2" : "=v"(r) : "v"(lo), "v"(hi));
  return r;
}

// ---------------- fused fp32 -> bf16 conversion (x + 4 weights) ----------------
__global__ void f2bf_all(const float* __restrict__ x, const float* __restrict__ wq,
                         const float* __restrict__ wk, const float* __restrict__ wv,
                         const float* __restrict__ wo, unsigned short* __restrict__ xb,
                         unsigned short* __restrict__ wb) {
  int blk = blockIdx.x;
  const float* src;
  unsigned short* dst;
  int rb;
  if (blk < 4096) { src = x; dst = xb; rb = blk; }
  else {
    int w = (blk - 4096) >> 10;
    src = w == 0 ? wq : w == 1 ? wk : w == 2 ? wv : wo;
    dst = wb + (size_t)w * 1048576;
    rb = (blk - 4096) & 1023;
  }
  int i = rb * 256 + threadIdx.x;  // float4 index
  float4 v = ((const float4*)src)[i];
  u16x4 o;
  o[0] = f2bf(v.x); o[1] = f2bf(v.y); o[2] = f2bf(v.z); o[3] = f2bf(v.w);
  ((u16x4*)dst)[i] = o;
}

// ---------------- NT GEMM: C[m,n] = sum_k A[m,k] * B[n,k] ----------------
template <bool F32OUT>
__global__ __launch_bounds__(256) void gemm_nt(
    const unsigned short* __restrict__ A,
    const unsigned short* __restrict__ Ball,
    void* __restrict__ Call,
    int K, int N, long long wstride, long long cstride) {
  __shared__ unsigned short As[128 * 64];
  __shared__ unsigned short Bs[128 * 64];
  const int tid = threadIdx.x;
  const int wv = tid >> 6, lane = tid & 63;
  const int g = lane >> 4, l16 = lane & 15;
  const int m0 = blockIdx.y * 128, n0 = blockIdx.x * 128;
  const unsigned short* B = Ball + (long long)blockIdx.z * wstride;
  const int wm = (wv >> 1) * 64, wn = (wv & 1) * 64;
  f32x4 acc[4][4] = {};

  for (int kt = 0; kt < K; kt += 64) {
    __syncthreads();
#pragma unroll
    for (int qq = 0; qq < 4; ++qq) {
      int rbase = wv * 32 + qq * 8;
      int r = rbase + (lane >> 3);
      int cs = ((lane & 7) ^ (r & 7)) * 8;  // pre-swizzled source chunk
      gload_lds16(A + (long long)(m0 + r) * K + kt + cs, &As[rbase * 64]);
      gload_lds16(B + (long long)(n0 + r) * K + kt + cs, &Bs[rbase * 64]);
    }
    __syncthreads();
#pragma unroll
    for (int ks = 0; ks < 2; ++ks) {
      bf16x8 af[4], bfr[4];
      const int cb = ks * 64 + g * 16;
#pragma unroll
      for (int mf = 0; mf < 4; ++mf) {
        int row = wm + mf * 16 + l16;
        af[mf] = *(const bf16x8*)((const char*)As + row * 128 + (cb ^ ((row & 7) << 4)));
      }
#pragma unroll
      for (int nf = 0; nf < 4; ++nf) {
        int row = wn + nf * 16 + l16;
        bfr[nf] = *(const bf16x8*)((const char*)Bs + row * 128 + (cb ^ ((row & 7) << 4)));
      }
#pragma unroll
      for (int mf = 0; mf < 4; ++mf)
#pragma unroll
        for (int nf = 0; nf < 4; ++nf)
          acc[mf][nf] = __builtin_amdgcn_mfma_f32_16x16x32_bf16(
              af[mf], bfr[nf], acc[mf][nf], 0, 0, 0);
    }
  }

#pragma unroll
  for (int mf = 0; mf < 4; ++mf)
#pragma unroll
    for (int nf = 0; nf < 4; ++nf)
#pragma unroll
      for (int r = 0; r < 4; ++r) {
        long long m = m0 + wm + mf * 16 + g * 4 + r;
        long long n = n0 + wn + nf * 16 + l16;
        float v = acc[mf][nf][r];
        if (F32OUT)
          ((float*)Call)[(long long)blockIdx.z * cstride + m * N + n] = v;
        else
          ((unsigned short*)Call)[(long long)blockIdx.z * cstride + m * N + n] = f2bf(v);
      }
}

// ---------------- flash attention: 4 waves, 128-row q-tile, shared LDS k-tiles ----
// grid (16, 16, 2), block 256. qt = 15 - bx (longest-first). All waves iterate the
// same k-tiles; K and V^T (8 KB each) staged via global_load_lds, double-buffered,
// prefetch issued at loop head so latency hides under compute.
// Swapped QK^T with 32x32x16 MFMA: S^T[key][q], col=lane&31=q.
// P redistributed in-register: v_cvt_pk_bf16_f32 + v_permlane32_swap_b32.
// PV: O^T[d][q] = sum VT[d][key] * P^T[key][q]; VT pre-transposed in global.
__global__ __launch_bounds__(256) void attn_kernel(
    const unsigned short* __restrict__ Qg,
    const unsigned short* __restrict__ Kg,
    const unsigned short* __restrict__ VTg,
    unsigned short* __restrict__ Og) {
  __shared__ unsigned short Kls[2][4096];  // [buf][key 64][d 64] (chunk-swizzled)
  __shared__ unsigned short Vls[2][4096];  // [buf][d 64][key 64] (chunk-swizzled)

  const int tid = threadIdx.x;
  const int wv = tid >> 6, lane = tid & 63;
  const int l32 = lane & 31, hi = lane >> 5;
  const int qt = 15 - blockIdx.x;
  const int h = blockIdx.y, b = blockIdx.z;
  const int q0 = qt * 128;
  const int q = q0 + wv * 32 + l32;

  const long long bh = (long long)b * SEQ * DIM + h * HDIM;
  const long long vbase = (long long)h * HDIM * 4096 + b * SEQ;

  // Q fragments (B-operand): B[col=q][k = hi*8+j], per 16-d slice
  const unsigned short* Qrow = Qg + (long long)(b * SEQ + q) * DIM + h * HDIM;
  bf16x8 qf[4];
#pragma unroll
  for (int ds = 0; ds < 4; ++ds)
    qf[ds] = *(const bf16x8*)(Qrow + ds * 16 + hi * 8);

  f32x16 acc0 = {}, acc1 = {};
  float m_run = -1e30f, l_run = 0.f;

  const int nt_blk = 2 * qt + 2;                 // tiles staged by the block
  const int nt_wv = 2 * qt + 1 + (wv >> 1);      // tiles this wave computes

  // stage: this wave loads K chunks {2wv,2wv+1} and V chunks {2wv,2wv+1}
  // (chunk j = 8 rows of 128 B; linear LDS dest, inverse-swizzled global source)
  const int sr = lane >> 3, sc = lane & 7;
#define STAGE(T, BUF)                                                          \
  {                                                                            \
    const int kv0s = (T) * 64;                                                 \
    _Pragma("unroll")                                                          \
    for (int s = 0; s < 2; ++s) {                                              \
      int j = wv * 2 + s;                                                      \
      int r = j * 8 + sr;                                                      \
      int cs = (sc ^ (r & 7)) * 8;                                             \
      gload_lds16(Kg + bh + (long long)(kv0s + r) * DIM + cs,                  \
                  &Kls[BUF][j * 512]);                                         \
      gload_lds16(VTg + vbase + (long long)r * 4096 + kv0s + cs,               \
                  &Vls[BUF][j * 512]);                                         \
    }                                                                          \
  }

  STAGE(0, 0);
  __syncthreads();

  for (int t = 0; t < nt_blk; ++t) {
    const int buf = t & 1;
    if (t + 1 < nt_blk) STAGE(t + 1, buf ^ 1);

    if (t < nt_wv) {
      const int kv0 = t * 64;
      // --- K fragments from LDS: A[row=key][k-chunk 2ds+hi] ---
      bf16x8 kf[8];
#pragma unroll
      for (int mf = 0; mf < 2; ++mf)
#pragma unroll
        for (int ds = 0; ds < 4; ++ds) {
          int row = mf * 32 + l32;
          kf[mf * 4 + ds] = *(const bf16x8*)((const char*)&Kls[buf][0] +
                                             row * 128 + (((ds << 1) | hi) ^ (row & 7)) * 16);
        }
      // --- QK^T ---
      f32x16 s0 = {}, s1 = {};
#pragma unroll
      for (int ds = 0; ds < 4; ++ds) {
        s0 = mfma32(kf[ds], qf[ds], s0);
        s1 = mfma32(kf[4 + ds], qf[ds], s1);
      }
      // --- V^T fragments from LDS (issue early; hides under softmax) ---
      bf16x8 vf[8];
#pragma unroll
      for (int dblk = 0; dblk < 2; ++dblk)
#pragma unroll
        for (int kks = 0; kks < 4; ++kks) {
          int row = dblk * 32 + l32;
          vf[dblk * 4 + kks] = *(const bf16x8*)((const char*)&Vls[buf][0] +
                                                row * 128 + (((kks << 1) | hi) ^ (row & 7)) * 16);
        }

      // --- causal mask (only tiles touching the diagonal) ---
      if (kv0 + 64 > q) {
#pragma unroll
        for (int r = 0; r < 16; ++r) {
          int kw = (r & 3) + 8 * (r >> 2) + 4 * hi;  // key within 32-block
          if (kv0 + kw > q) s0[r] = -1e30f;
          if (kv0 + 32 + kw > q) s1[r] = -1e30f;
        }
      }

      // --- online softmax: TREE max (depth 5) ---
      float mt[16];
#pragma unroll
      for (int i = 0; i < 16; ++i) mt[i] = fmaxf(s0[i], s1[i]);
#pragma unroll
      for (int off = 8; off; off >>= 1)
#pragma unroll
        for (int i = 0; i < off; ++i) mt[i] = fmaxf(mt[i], mt[i + off]);
      float pm = fmaxf(mt[0], __shfl_xor(mt[0], 32));

      if (!__all(pm - m_run <= 44.3614f)) {  // defer-max: skip rescale if growth < 8/C2
        float m_new = fmaxf(m_run, pm);
        float rs = exp2f((m_run - m_new) * C2);
        l_run *= rs;
#pragma unroll
        for (int r = 0; r < 16; ++r) { acc0[r] *= rs; acc1[r] *= rs; }
        m_run = m_new;
      }
      const float mc = m_run * C2;
      float at[16];
#pragma unroll
      for (int r = 0; r < 16; ++r) {
        float p0 = exp2f(s0[r] * C2 - mc);
        float p1 = exp2f(s1[r] * C2 - mc);
        s0[r] = p0; s1[r] = p1;
        at[r] = p0 + p1;
      }
#pragma unroll
      for (int off = 8; off; off >>= 1)
#pragma unroll
        for (int i = 0; i < off; ++i) at[i] += at[i + off];
      l_run += at[0] + __shfl_xor(at[0], 32);

      // --- P -> bf16 B-fragments (in-register) + PV ---
#pragma unroll
      for (int kks = 0; kks < 4; ++kks) {
        const int base = (kks & 1) * 8;
        unsigned a0, a1, a2, a3;
        if (kks < 2) {
          a0 = cvtpk(s0[base + 0], s0[base + 1]);
          a1 = cvtpk(s0[base + 2], s0[base + 3]);
          a2 = cvtpk(s0[base + 4], s0[base + 5]);
          a3 = cvtpk(s0[base + 6], s0[base + 7]);
        } else {
          a0 = cvtpk(s1[base + 0], s1[base + 1]);
          a1 = cvtpk(s1[base + 2], s1[base + 3]);
          a2 = cvtpk(s1[base + 4], s1[base + 5]);
          a3 = cvtpk(s1[base + 6], s1[base + 7]);
        }
        asm("v_permlane32_swap_b32 %0, %1" : "+v"(a0), "+v"(a2));
        asm("v_permlane32_swap_b32 %0, %1" : "+v"(a1), "+v"(a3));
        union { unsigned u[4]; bf16x8 v; } pf;
        pf.u[0] = a0; pf.u[1] = a1; pf.u[2] = a2; pf.u[3] = a3;
        acc0 = mfma32(vf[kks], pf.v, acc0);
        acc1 = mfma32(vf[4 + kks], pf.v, acc1);
      }
    }
    __syncthreads();  // drains prefetch (vmcnt 0) + guards buffer reuse
  }

  // --- epilogue: O[b, q, h*64 + d] = acc^T / l ---
  const float inv_l = 1.0f / l_run;
  unsigned short* Orow = Og + (long long)(b * SEQ + q) * DIM + h * HDIM;
#pragma unroll
  for (int dblk = 0; dblk < 2; ++dblk) {
#pragma unroll
    for (int g4 = 0; g4 < 4; ++g4) {
      u16x4 o;
#pragma unroll
      for (int j = 0; j < 4; ++j) {
        float v = (dblk ? acc1[g4 * 4 + j] : acc0[g4 * 4 + j]) * inv_l;
        o[j] = f2bf(v);
      }
      *(u16x4*)(Orow + dblk * 32 + 8 * g4 + 4 * hi) = o;
    }
  }
}

// ---------------- launcher ----------------
extern "C" void kernel_launch(void* const* d_in, const int* in_sizes, int n_in,
                              void* d_out, int out_size, void* d_ws, size_t ws_size,
                              hipStream_t stream) {
  const float* x   = (const float*)d_in[0];
  const float* wq  = (const float*)d_in[2];
  const float* wk  = (const float*)d_in[3];
  const float* wv_ = (const float*)d_in[4];
  const float* wo  = (const float*)d_in[5];

  unsigned short* xb  = (unsigned short*)d_ws;            // [4096][1024]
  unsigned short* wb  = xb + (size_t)4096 * 1024;         // [4][1024][1024] q,k,v,o
  unsigned short* qkv = wb + (size_t)4 * 1024 * 1024;     // Q,K [4096][1024]; VT [1024][4096]
  unsigned short* ao  = qkv + (size_t)3 * 4096 * 1024;    // [4096][1024]

  f2bf_all<<<8192, 256, 0, stream>>>(x, wq, wk, wv_, wo, xb, wb);

  // Q,K projections (z selects weight/output)
  gemm_nt<false><<<dim3(8, 32, 2), 256, 0, stream>>>(
      xb, wb, qkv, 1024, 1024, 1048576LL, 4194304LL);

  // V^T projection: C[n_v][token] = sum_k wv[n_v,k] x[token,k]  (A/B roles swapped)
  gemm_nt<false><<<dim3(32, 8, 1), 256, 0, stream>>>(
      wb + 2 * 1048576, xb, qkv + 2 * 4194304, 1024, 4096, 0LL, 0LL);

  attn_kernel<<<dim3(16, 16, 2), 256, 0, stream>>>(
      qkv, qkv + 4194304, qkv + 2 * 4194304, ao);

  // output projection -> fp32 d_out
  gemm_nt<true><<<dim3(8, 32, 1), 256, 0, stream>>>(
      ao, wb + 3145728, d_out, 1024, 1024, 0LL, 0LL);
}